// Round 1
// baseline (281.239 us; speedup 1.0000x reference)
//
#include <hip/hip_runtime.h>
#include <math.h>

#define B_ 64
#define N_ 512
#define R_ (B_*N_)                  // 32768 rows
#define INV_S 0.9995003746877732f   // 1/sqrt(1+1e-3)

__device__ __forceinline__ float fast_tanh(float y){
  return 1.f - 2.f*__builtin_amdgcn_rcpf(1.f + __expf(2.f*y));
}
__device__ __forceinline__ float fast_sigmoid(float v){
  return __builtin_amdgcn_rcpf(1.f + __expf(-v));
}

struct GnnArgs {
  const float* xx;
  const float* emb1; const float* emb2; const float* emb3;
  const float* A0;  const float* b0;
  const float* Ar;  const float* br;
  const float* bng; const float* bnb;
  float4* cb0; float4* cb1;          // coords double-buffer (global)
  unsigned int* bar;                 // per-b barrier counters (64 x stride 32)
  float* xfinal;                     // final x for dense0 (R_ x 64)
};

// ---------------------------------------------------------------------------
// All 5 GNN layers fused into ONE cooperative kernel.
// grid (64,8): blockIdx.x = b  (so the 8 blocks of one b land on the same XCD
// under round-robin dispatch -> coords stay L2-local), blockIdx.y = jc.
// 512 threads, LDS 70.8 KB -> exactly 2 blocks/CU -> 512 blocks co-resident.
//
// x rows (the block's own 64 rows) live in a double-buffered LDS tile across
// all layers; the old version round-tripped 8.4 MB write + 8.4 MB read per
// layer through HBM. Only the last-4-feature coords cross blocks, via global
// cb0/cb1 published with a per-b 8-block barrier:
//   syncthreads -> tid0: agent-release fence + atomicAdd   (publish coords)
//   all threads: stage next layer's A (overlaps the wait)
//   tid0: relaxed spin until count >= 8*k, agent-acquire fence
//   syncthreads
// Counters are monotone (target 8k) so barrier skew is safe; they are zeroed
// by a hipMemsetAsync before the launch (workspace is poisoned, not zeroed).
// Arithmetic is op-for-op identical to the unfused version (absmax stays 0).
// ---------------------------------------------------------------------------
__global__ __launch_bounds__(512, 4) void gnn_fused(GnnArgs g)
{
  __shared__ float alo[64*64];          // 16 KB
  __shared__ float ahi[64*64];          // 16 KB
  __shared__ float xsb[2][64*68];       // 34 KB; stride 68: float4-aligned,
                                        // rows differ by 136%32=8 banks
  __shared__ float spart[512], tpart[512];
  __shared__ float scl[64], tcl[64], ml[64];

  const int tid   = threadIdx.x;
  const int b     = blockIdx.x;          // 0..63
  const int jc    = blockIdx.y;          // 0..7
  const int jloc  = jc*64;
  const int rbase = b*N_;
  const int cg = tid & 15, rg = tid >> 4;
  const int o0 = cg*4,  lr0 = rg*2;
  unsigned int* barp = g.bar + b*32;     // 128B-strided counters

  int cur = 0;
  for (int k = 0; k < 5; ++k){
    const float* A;  const float* bi;  int K, KP;
    if (k == 0){ A = g.A0;                        bi = g.b0;           K = 33; KP = 36; }
    else       { A = g.Ar + (size_t)(k-1)*129*64; bi = g.br + (k-1)*64; K = 64; KP = 64; }
    const float* gam = g.bng + k*64;
    const float* bet = g.bnb + k*64;

    // ---- stage A into LDS (+ build x0/mask at k==0); inter-block barrier k>=1 ----
    if (k == 0){
      for (int idx = tid; idx < 36*64; idx += 512){
        int f = idx >> 6;
        alo[idx] = (f < 33) ? A[idx] : 0.f;
        ahi[idx] = (f < 33) ? A[33*64 + idx] : 0.f;
      }
      if (tid < 64){
        const float* row = g.xx + (size_t)(rbase + jloc + tid)*30;
        float v[30];
#pragma unroll
        for (int i=0;i<30;i++) v[i] = row[i];
        int i1 = (int)fabsf(v[27]);
        int i2 = (int)fabsf(v[28]);
        int i3 = (int)fabsf(v[29]);
        float* o = &xsb[0][tid*68];
        o[0]=g.emb1[i1*2+0]; o[1]=g.emb1[i1*2+1];
        o[2]=g.emb2[i2*2+0]; o[3]=g.emb2[i2*2+1];
        o[4]=g.emb3[i3*2+0]; o[5]=g.emb3[i3*2+1];
#pragma unroll
        for (int i=0;i<27;i++) o[6+i] = v[i];
        o[33]=0.f; o[34]=0.f; o[35]=0.f;
        ml[tid] = v[0];
      }
    } else {
      __syncthreads();                 // prev GEMM done: alo/ahi free, cb written
      if (tid == 0){
        __builtin_amdgcn_fence(__ATOMIC_RELEASE, "agent");
        __hip_atomic_fetch_add(barp, 1u, __ATOMIC_RELAXED, __HIP_MEMORY_SCOPE_AGENT);
      }
      {                                 // stage next A while tid0 waits
        const float4* A4 = (const float4*)A;
        float4* alo4 = (float4*)alo;
        float4* ahi4 = (float4*)ahi;
        for (int idx = tid; idx < 1024; idx += 512){
          alo4[idx] = A4[idx];
          ahi4[idx] = A4[1024 + idx];
        }
      }
      if (tid == 0){
        unsigned int tgt = 8u*(unsigned int)k;
        while (__hip_atomic_load(barp, __ATOMIC_RELAXED, __HIP_MEMORY_SCOPE_AGENT) < tgt)
          __builtin_amdgcn_s_sleep(2);
        __builtin_amdgcn_fence(__ATOMIC_ACQUIRE, "agent");
      }
      __syncthreads();                 // coords from all 8 blocks now visible
    }

    // ---- S/T partials: jj = tid&63 (row), ic = tid>>6 (64-i chunk) ----
    {
      int jj = tid & 63, ic = tid >> 6, base = ic*64;
      float Ss = 0.f, Ts = 0.f;
      if (k == 0){
        const float* xb = g.xx + (size_t)rbase*30;
        float cjx = xb[(jloc+jj)*30 + 25];
        float cjy = xb[(jloc+jj)*30 + 26];
#pragma unroll 8
        for (int i=0;i<64;i++){
          float cix = xb[(base+i)*30 + 25];    // wave-uniform address
          float ciy = xb[(base+i)*30 + 26];
          float d0 = cjx-cix, d1 = cjy-ciy;
          float dist = d0*d0 + d1*d1;
          float w = __expf(-10.f*dist);
          Ss += w; Ts += dist*w;
        }
      } else {
        const float4* cbr = ((k & 1) ? g.cb0 : g.cb1) + rbase;
        float4 cj = *(const float4*)&xsb[cur][jj*68 + 60];   // own coords from LDS
#pragma unroll 8
        for (int i=0;i<64;i++){
          float4 ci = cbr[base+i];             // wave-uniform address
          float d0 = cj.x-ci.x, d1 = cj.y-ci.y, d2 = cj.z-ci.z, d3 = cj.w-ci.w;
          float dist = d0*d0 + d1*d1 + d2*d2 + d3*d3;
          float w = __expf(-10.f*dist);
          Ss += w; Ts += dist*w;
        }
      }
      spart[tid] = Ss;
      tpart[tid] = Ts;
    }
    __syncthreads();                   // also covers A/x0/ml staging at k==0

    if (tid < 64){
      float S = 0.f, T = 0.f;
#pragma unroll
      for (int c=0;c<8;c++){
        S += spart[tid + 64*c];
        T += tpart[tid + 64*c];
      }
      float m = ml[tid];
      scl[tid] = m*S - 1.f;
      tcl[tid] = m*T;
    }
    __syncthreads();

    // ---- GEMM: thread = 2 rows x 4 outs, lo+hi matrices; x from LDS ----
    const float* xsrc = &xsb[cur][0];
    float4 acc1[2], acc2[2];
#pragma unroll
    for (int rr=0;rr<2;rr++){
      acc1[rr] = make_float4(0.f,0.f,0.f,0.f);
      acc2[rr] = make_float4(0.f,0.f,0.f,0.f);
    }
#pragma unroll 2
    for (int kc = 0; kc < KP; kc += 4){
      float4 a1[4], a2[4], xv[2];
#pragma unroll
      for (int uu=0;uu<4;uu++){
        a1[uu] = *(const float4*)&alo[(kc+uu)*64 + o0];
        a2[uu] = *(const float4*)&ahi[(kc+uu)*64 + o0];
      }
#pragma unroll
      for (int rr=0;rr<2;rr++)
        xv[rr] = *(const float4*)&xsrc[(lr0+rr)*68 + kc];
#pragma unroll
      for (int uu=0;uu<4;uu++){
#pragma unroll
        for (int rr=0;rr<2;rr++){
          float xu = ((const float*)&xv[rr])[uu];
          acc1[rr].x = fmaf(xu, a1[uu].x, acc1[rr].x);
          acc1[rr].y = fmaf(xu, a1[uu].y, acc1[rr].y);
          acc1[rr].z = fmaf(xu, a1[uu].z, acc1[rr].z);
          acc1[rr].w = fmaf(xu, a1[uu].w, acc1[rr].w);
          acc2[rr].x = fmaf(xu, a2[uu].x, acc2[rr].x);
          acc2[rr].y = fmaf(xu, a2[uu].y, acc2[rr].y);
          acc2[rr].z = fmaf(xu, a2[uu].z, acc2[rr].z);
          acc2[rr].w = fmaf(xu, a2[uu].w, acc2[rr].w);
        }
      }
    }

    float4 alast = *(const float4*)&A[(size_t)2*K*64 + o0];
    float4 bo = *(const float4*)&bi[o0];
    float4 go = *(const float4*)&gam[o0];
    float4 bb = *(const float4*)&bet[o0];
    float4* cbw = (k & 1) ? g.cb1 : g.cb0;
#pragma unroll
    for (int rr=0;rr<2;rr++){
      int lr = lr0 + rr;
      float sc = scl[lr], tc = tcl[lr], m = ml[lr];
      float4 v;
      v.x = (acc1[rr].x + sc*acc2[rr].x + tc*alast.x + bo.x)*m;
      v.y = (acc1[rr].y + sc*acc2[rr].y + tc*alast.y + bo.y)*m;
      v.z = (acc1[rr].z + sc*acc2[rr].z + tc*alast.z + bo.z)*m;
      v.w = (acc1[rr].w + sc*acc2[rr].w + tc*alast.w + bo.w)*m;
      float4 t;
      t.x = fast_tanh(go.x*(v.x*INV_S) + bb.x);
      t.y = fast_tanh(go.y*(v.y*INV_S) + bb.y);
      t.z = fast_tanh(go.z*(v.z*INV_S) + bb.z);
      t.w = fast_tanh(go.w*(v.w*INV_S) + bb.w);
      if (k < 4){
        *(float4*)&xsb[cur^1][lr*68 + o0] = t;
        if (cg == 15) cbw[rbase + jloc + lr] = t;    // coords (cols 60..63)
      } else {
        *(float4*)&g.xfinal[(size_t)(rbase + jloc + lr)*64 + o0] = t;
      }
    }
    cur ^= 1;
  }
}

// ---------------------------------------------------------------------------
// dense0 split-K partials (unchanged).
// ---------------------------------------------------------------------------
__global__ __launch_bounds__(256) void dense0_partial(
    const float* __restrict__ X, const float* __restrict__ W,
    float* __restrict__ partial)
{
  __shared__ float xt[64*32];
  __shared__ float wt[32*128];
  int tid = threadIdx.x;
  int k0 = blockIdx.x*128;
  int og = (tid & 15)*8;
  int rg = (tid >> 4)*4;
  float acc[4][8];
#pragma unroll
  for (int a=0;a<4;a++)
#pragma unroll
    for (int u=0;u<8;u++) acc[a][u]=0.f;
  for (int kt = 0; kt < 128; kt += 32){
    __syncthreads();
    for (int idx = tid; idx < 512; idx += 256){
      int r = idx >> 3, kq = idx & 7;
      *(float4*)&xt[r*32 + kq*4] =
          *(const float4*)&X[(size_t)r*32768 + k0 + kt + kq*4];
    }
    {
      const float4* Wc = (const float4*)&W[(size_t)(k0+kt)*128];
      float4* wt4 = (float4*)wt;
      for (int idx = tid; idx < 1024; idx += 256) wt4[idx] = Wc[idx];
    }
    __syncthreads();
#pragma unroll 4
    for (int k=0;k<32;k++){
      float4 w0 = *(const float4*)&wt[k*128 + og];
      float4 w1 = *(const float4*)&wt[k*128 + og + 4];
      float xs[4];
#pragma unroll
      for (int rr=0;rr<4;rr++) xs[rr] = xt[(rg+rr)*32 + k];
#pragma unroll
      for (int rr=0;rr<4;rr++){
        acc[rr][0] = fmaf(xs[rr], w0.x, acc[rr][0]);
        acc[rr][1] = fmaf(xs[rr], w0.y, acc[rr][1]);
        acc[rr][2] = fmaf(xs[rr], w0.z, acc[rr][2]);
        acc[rr][3] = fmaf(xs[rr], w0.w, acc[rr][3]);
        acc[rr][4] = fmaf(xs[rr], w1.x, acc[rr][4]);
        acc[rr][5] = fmaf(xs[rr], w1.y, acc[rr][5]);
        acc[rr][6] = fmaf(xs[rr], w1.z, acc[rr][6]);
        acc[rr][7] = fmaf(xs[rr], w1.w, acc[rr][7]);
      }
    }
  }
  float* pb = partial + (size_t)blockIdx.x*8192;
#pragma unroll
  for (int rr=0;rr<4;rr++){
    *(float4*)&pb[(rg+rr)*128 + og]     = *(float4*)&acc[rr][0];
    *(float4*)&pb[(rg+rr)*128 + og + 4] = *(float4*)&acc[rr][4];
  }
}

// ---------------------------------------------------------------------------
// Head (unchanged).
// ---------------------------------------------------------------------------
__global__ __launch_bounds__(256) void dense_head(
    const float* __restrict__ partial,
    const float* __restrict__ db0, const float* __restrict__ dg0,
    const float* __restrict__ dbb0,
    const float* __restrict__ dW1, const float* __restrict__ db1,
    const float* __restrict__ dg1, const float* __restrict__ dbb1,
    const float* __restrict__ W2, const float* __restrict__ b2,
    float* __restrict__ out)
{
  __shared__ float sred[256];
  __shared__ float h[128];
  __shared__ float red0[128], red1[128];
  int tid = threadIdx.x;
  int b = blockIdx.x;
  int o = tid & 127, ph = tid >> 7;
  float s = 0.f;
#pragma unroll 16
  for (int p = ph*128; p < ph*128+128; p++)
    s += partial[(size_t)p*8192 + b*128 + o];
  sred[tid] = s;
  __syncthreads();
  if (tid < 128){
    float sum = sred[tid] + sred[tid+128];
    float v = dg0[tid]*((sum + db0[tid])*INV_S) + dbb0[tid];
    h[tid] = fast_sigmoid(v);
  }
  __syncthreads();
  if (tid < 128){
    float acc = 0.f;
#pragma unroll 8
    for (int k=0;k<128;k++) acc = fmaf(h[k], dW1[k*128 + tid], acc);
    float v = dg1[tid]*((acc + db1[tid])*INV_S) + dbb1[tid];
    float h1 = fast_sigmoid(v);
    red0[tid] = h1 * W2[tid*2+0];
    red1[tid] = h1 * W2[tid*2+1];
  }
  __syncthreads();
  for (int st=64; st>0; st>>=1){
    if (tid < st){ red0[tid] += red0[tid+st]; red1[tid] += red1[tid+st]; }
    __syncthreads();
  }
  if (tid == 0){
    out[b*4+0] = red0[0] + b2[0];
    out[b*4+1] = red1[0] + b2[1];
    out[b*4+2] = 0.f;
    out[b*4+3] = 0.f;
  }
}

// ---------------------------------------------------------------------------
extern "C" void kernel_launch(void* const* d_in, const int* in_sizes, int n_in,
                              void* d_out, int out_size, void* d_ws, size_t ws_size,
                              hipStream_t stream)
{
  const float* xx   = (const float*)d_in[0];
  const float* emb1 = (const float*)d_in[1];
  const float* emb2 = (const float*)d_in[2];
  const float* emb3 = (const float*)d_in[3];
  const float* A0   = (const float*)d_in[4];
  const float* b0   = (const float*)d_in[5];
  const float* Ar   = (const float*)d_in[6];   // (4,129,64)
  const float* br   = (const float*)d_in[7];   // (4,64)
  const float* bng  = (const float*)d_in[8];   // (5,64)
  const float* bnb  = (const float*)d_in[9];   // (5,64)
  const float* dW0  = (const float*)d_in[10];  // (32768,128)
  const float* db0  = (const float*)d_in[11];
  const float* dW1  = (const float*)d_in[12];  // (128,128)
  const float* db1  = (const float*)d_in[13];
  const float* dbg  = (const float*)d_in[14];  // (2,128)
  const float* dbb  = (const float*)d_in[15];
  const float* W2   = (const float*)d_in[16];  // (128,2)
  const float* b2   = (const float*)d_in[17];

  float* ws = (float*)d_ws;
  float*  xA      = ws;                               // 32768*64
  float*  partial = xA + (size_t)R_*64;               // 256*8192
  float4* cb0     = (float4*)(partial + (size_t)256*8192);  // 32768 float4
  float4* cb1     = cb0 + R_;                         // 32768 float4
  unsigned int* bar = (unsigned int*)(cb1 + R_);      // 64*32 uints

  // barrier counters must start at 0 (workspace is poisoned, not zeroed)
  hipMemsetAsync(bar, 0, 64*32*sizeof(unsigned int), stream);

  GnnArgs ga;
  ga.xx = xx; ga.emb1 = emb1; ga.emb2 = emb2; ga.emb3 = emb3;
  ga.A0 = A0; ga.b0 = b0; ga.Ar = Ar; ga.br = br;
  ga.bng = bng; ga.bnb = bnb;
  ga.cb0 = cb0; ga.cb1 = cb1; ga.bar = bar; ga.xfinal = xA;

  void* kargs[] = { (void*)&ga };
  if (hipLaunchCooperativeKernel((void*)gnn_fused, dim3(64,8), dim3(512),
                                 kargs, 0, stream) != hipSuccess){
    // grid exactly fits (2 blocks/CU x 256 CU); fall back to plain launch
    hipLaunchKernelGGL(gnn_fused, dim3(64,8), dim3(512), 0, stream, ga);
  }

  dense0_partial<<<256, 256, 0, stream>>>(xA, dW0, partial);
  dense_head<<<B_, 256, 0, stream>>>(partial, db0, dbg, dbb,
                                     dW1, db1, dbg + 128, dbb + 128,
                                     W2, b2, (float*)d_out);
}

// Round 2
// 219.065 us; speedup vs baseline: 1.2838x; 1.2838x over previous
//
#include <hip/hip_runtime.h>
#include <math.h>

#define B_ 64
#define N_ 512
#define R_ (B_*N_)                  // 32768 rows
#define INV_S 0.9995003746877732f   // 1/sqrt(1+1e-3)

__device__ __forceinline__ float fast_tanh(float y){
  return 1.f - 2.f*__builtin_amdgcn_rcpf(1.f + __expf(2.f*y));
}
__device__ __forceinline__ float fast_sigmoid(float v){
  return __builtin_amdgcn_rcpf(1.f + __expf(-v));
}

struct GnnArgs {
  const float* xx;
  const float* emb1; const float* emb2; const float* emb3;
  const float* A0;  const float* b0;
  const float* Ar;  const float* br;
  const float* bng; const float* bnb;
  float4* cb0; float4* cb1;          // coords double-buffer (global)
  unsigned int* bar;                 // per-b barrier counters (64 x stride 32)
  float* xfinal;                     // final x for dense0 (R_ x 64)
};

// ---------------------------------------------------------------------------
// All 5 GNN layers fused, PLAIN launch (round 1's hipLaunchCooperativeKernel
// is suspected of capturing with device-exclusive drain semantics -> ~100us
// of graph bubbles). Co-residency of all 512 blocks is guaranteed by
// arithmetic instead: LDS ~63KB -> exactly 2 blocks/CU x 256 CU = 512 slots.
//
// grid (64,8): blockIdx.x = b. Linear block id = b + 64*jc; 64 % 8 == 0, so
// all 8 blocks of one b land on the SAME XCD under round-robin dispatch ->
// cb coords reads and barrier spins are L2-local.
//
// Changes vs round 1:
//  * cl[512] (8KB LDS): per-layer stage of ALL coords of this b (one
//    coalesced float4/thread), replacing 64 uniform-address GLOBAL loads
//    per wave in the S/T loop with LDS broadcast reads (no latency wall).
//  * x tile single-buffered in place (GEMM reads only own rows; sync before
//    overwrite) -> LDS 72.7KB -> 63KB, funding cl at 2 blocks/CU.
//  * k=0 S/T unified into the 4-component path with z=w=0 (exact +0.0 adds,
//    bitwise identical).
// Arithmetic unchanged -> absmax stays 0.
// ---------------------------------------------------------------------------
__global__ __launch_bounds__(512, 4) void gnn_fused(GnnArgs g)
{
  __shared__ float alo[64*64];          // 16 KB
  __shared__ float ahi[64*64];          // 16 KB
  __shared__ float xs[64*68];           // 17 KB, stride 68: float4-aligned
  __shared__ float4 cl[512];            // 8 KB: coords of all 512 rows of b
  __shared__ float spart[512], tpart[512];
  __shared__ float scl[64], tcl[64], ml[64];

  const int tid   = threadIdx.x;
  const int b     = blockIdx.x;          // 0..63
  const int jc    = blockIdx.y;          // 0..7
  const int jloc  = jc*64;
  const int rbase = b*N_;
  const int cg = tid & 15, rg = tid >> 4;
  const int o0 = cg*4,  lr0 = rg*2;
  unsigned int* barp = g.bar + b*32;     // 128B-strided counters

  for (int k = 0; k < 5; ++k){
    const float* A;  const float* bi;  int K, KP;
    if (k == 0){ A = g.A0;                        bi = g.b0;            K = 33; KP = 36; }
    else       { A = g.Ar + (size_t)(k-1)*129*64; bi = g.br + (k-1)*64; K = 64; KP = 64; }
    const float* gam = g.bng + k*64;
    const float* bet = g.bnb + k*64;

    // ---- stage A + coords (+ build x0/mask at k==0); block-barrier k>=1 ----
    if (k == 0){
      for (int idx = tid; idx < 36*64; idx += 512){
        int f = idx >> 6;
        alo[idx] = (f < 33) ? A[idx] : 0.f;
        ahi[idx] = (f < 33) ? A[33*64 + idx] : 0.f;
      }
      {
        const float* xr = g.xx + (size_t)(rbase + tid)*30;
        cl[tid] = make_float4(xr[25], xr[26], 0.f, 0.f);
      }
      if (tid < 64){
        const float* row = g.xx + (size_t)(rbase + jloc + tid)*30;
        float v[30];
#pragma unroll
        for (int i=0;i<30;i++) v[i] = row[i];
        int i1 = (int)fabsf(v[27]);
        int i2 = (int)fabsf(v[28]);
        int i3 = (int)fabsf(v[29]);
        float* o = &xs[tid*68];
        o[0]=g.emb1[i1*2+0]; o[1]=g.emb1[i1*2+1];
        o[2]=g.emb2[i2*2+0]; o[3]=g.emb2[i2*2+1];
        o[4]=g.emb3[i3*2+0]; o[5]=g.emb3[i3*2+1];
#pragma unroll
        for (int i=0;i<27;i++) o[6+i] = v[i];
        o[33]=0.f; o[34]=0.f; o[35]=0.f;
        ml[tid] = v[0];
      }
    } else {
      __syncthreads();                 // epilogue writes done (cb stores drained)
      if (tid == 0){
        __builtin_amdgcn_fence(__ATOMIC_RELEASE, "agent");
        __hip_atomic_fetch_add(barp, 1u, __ATOMIC_RELAXED, __HIP_MEMORY_SCOPE_AGENT);
      }
      {                                 // stage next A while tid0 waits
        const float4* A4 = (const float4*)A;
        float4* alo4 = (float4*)alo;
        float4* ahi4 = (float4*)ahi;
        for (int idx = tid; idx < 1024; idx += 512){
          alo4[idx] = A4[idx];
          ahi4[idx] = A4[1024 + idx];
        }
      }
      if (tid == 0){
        unsigned int tgt = 8u*(unsigned int)k;
        while (__hip_atomic_load(barp, __ATOMIC_RELAXED, __HIP_MEMORY_SCOPE_AGENT) < tgt)
          __builtin_amdgcn_s_sleep(2);
        __builtin_amdgcn_fence(__ATOMIC_ACQUIRE, "agent");
      }
      __syncthreads();                 // coords from all 8 blocks now visible
      const float4* cbr = ((k & 1) ? g.cb0 : g.cb1) + rbase;
      cl[tid] = cbr[tid];              // coalesced stage of all 512 coords
    }
    __syncthreads();                   // cl (+ A/x0/ml at k==0) ready

    // ---- S/T partials: jj = tid&63 (row), ic = tid>>6 (64-i chunk).
    //      cl reads are wave-uniform -> LDS broadcast, conflict-free. ----
    {
      int jj = tid & 63, ic = tid >> 6, base = ic*64;
      float4 cj = cl[jloc + jj];
      float Ss = 0.f, Ts = 0.f;
#pragma unroll 8
      for (int i=0;i<64;i++){
        float4 ci = cl[base+i];
        float d0 = cj.x-ci.x, d1 = cj.y-ci.y, d2 = cj.z-ci.z, d3 = cj.w-ci.w;
        float dist = d0*d0 + d1*d1 + d2*d2 + d3*d3;
        float w = __expf(-10.f*dist);
        Ss += w; Ts += dist*w;
      }
      spart[tid] = Ss;
      tpart[tid] = Ts;
    }
    __syncthreads();

    if (tid < 64){
      float S = 0.f, T = 0.f;
#pragma unroll
      for (int c=0;c<8;c++){
        S += spart[tid + 64*c];
        T += tpart[tid + 64*c];
      }
      float m = ml[tid];
      scl[tid] = m*S - 1.f;
      tcl[tid] = m*T;
    }
    __syncthreads();

    // ---- GEMM: thread = 2 rows x 4 outs, lo+hi matrices; x from LDS ----
    float4 acc1[2], acc2[2];
#pragma unroll
    for (int rr=0;rr<2;rr++){
      acc1[rr] = make_float4(0.f,0.f,0.f,0.f);
      acc2[rr] = make_float4(0.f,0.f,0.f,0.f);
    }
#pragma unroll 2
    for (int kc = 0; kc < KP; kc += 4){
      float4 a1[4], a2[4], xv[2];
#pragma unroll
      for (int uu=0;uu<4;uu++){
        a1[uu] = *(const float4*)&alo[(kc+uu)*64 + o0];
        a2[uu] = *(const float4*)&ahi[(kc+uu)*64 + o0];
      }
#pragma unroll
      for (int rr=0;rr<2;rr++)
        xv[rr] = *(const float4*)&xs[(lr0+rr)*68 + kc];
#pragma unroll
      for (int uu=0;uu<4;uu++){
#pragma unroll
        for (int rr=0;rr<2;rr++){
          float xu = ((const float*)&xv[rr])[uu];
          acc1[rr].x = fmaf(xu, a1[uu].x, acc1[rr].x);
          acc1[rr].y = fmaf(xu, a1[uu].y, acc1[rr].y);
          acc1[rr].z = fmaf(xu, a1[uu].z, acc1[rr].z);
          acc1[rr].w = fmaf(xu, a1[uu].w, acc1[rr].w);
          acc2[rr].x = fmaf(xu, a2[uu].x, acc2[rr].x);
          acc2[rr].y = fmaf(xu, a2[uu].y, acc2[rr].y);
          acc2[rr].z = fmaf(xu, a2[uu].z, acc2[rr].z);
          acc2[rr].w = fmaf(xu, a2[uu].w, acc2[rr].w);
        }
      }
    }
    __syncthreads();                   // all xs reads done -> in-place write ok

    float4 alast = *(const float4*)&A[(size_t)2*K*64 + o0];
    float4 bo = *(const float4*)&bi[o0];
    float4 go = *(const float4*)&gam[o0];
    float4 bb = *(const float4*)&bet[o0];
    float4* cbw = (k & 1) ? g.cb1 : g.cb0;
#pragma unroll
    for (int rr=0;rr<2;rr++){
      int lr = lr0 + rr;
      float sc = scl[lr], tc = tcl[lr], m = ml[lr];
      float4 v;
      v.x = (acc1[rr].x + sc*acc2[rr].x + tc*alast.x + bo.x)*m;
      v.y = (acc1[rr].y + sc*acc2[rr].y + tc*alast.y + bo.y)*m;
      v.z = (acc1[rr].z + sc*acc2[rr].z + tc*alast.z + bo.z)*m;
      v.w = (acc1[rr].w + sc*acc2[rr].w + tc*alast.w + bo.w)*m;
      float4 t;
      t.x = fast_tanh(go.x*(v.x*INV_S) + bb.x);
      t.y = fast_tanh(go.y*(v.y*INV_S) + bb.y);
      t.z = fast_tanh(go.z*(v.z*INV_S) + bb.z);
      t.w = fast_tanh(go.w*(v.w*INV_S) + bb.w);
      if (k < 4){
        *(float4*)&xs[lr*68 + o0] = t;
        if (cg == 15) cbw[rbase + jloc + lr] = t;    // coords (cols 60..63)
      } else {
        *(float4*)&g.xfinal[(size_t)(rbase + jloc + lr)*64 + o0] = t;
      }
    }
  }
}

// ---------------------------------------------------------------------------
// dense0 split-K partials (unchanged).
// ---------------------------------------------------------------------------
__global__ __launch_bounds__(256) void dense0_partial(
    const float* __restrict__ X, const float* __restrict__ W,
    float* __restrict__ partial)
{
  __shared__ float xt[64*32];
  __shared__ float wt[32*128];
  int tid = threadIdx.x;
  int k0 = blockIdx.x*128;
  int og = (tid & 15)*8;
  int rg = (tid >> 4)*4;
  float acc[4][8];
#pragma unroll
  for (int a=0;a<4;a++)
#pragma unroll
    for (int u=0;u<8;u++) acc[a][u]=0.f;
  for (int kt = 0; kt < 128; kt += 32){
    __syncthreads();
    for (int idx = tid; idx < 512; idx += 256){
      int r = idx >> 3, kq = idx & 7;
      *(float4*)&xt[r*32 + kq*4] =
          *(const float4*)&X[(size_t)r*32768 + k0 + kt + kq*4];
    }
    {
      const float4* Wc = (const float4*)&W[(size_t)(k0+kt)*128];
      float4* wt4 = (float4*)wt;
      for (int idx = tid; idx < 1024; idx += 256) wt4[idx] = Wc[idx];
    }
    __syncthreads();
#pragma unroll 4
    for (int k=0;k<32;k++){
      float4 w0 = *(const float4*)&wt[k*128 + og];
      float4 w1 = *(const float4*)&wt[k*128 + og + 4];
      float xs[4];
#pragma unroll
      for (int rr=0;rr<4;rr++) xs[rr] = xt[(rg+rr)*32 + k];
#pragma unroll
      for (int rr=0;rr<4;rr++){
        acc[rr][0] = fmaf(xs[rr], w0.x, acc[rr][0]);
        acc[rr][1] = fmaf(xs[rr], w0.y, acc[rr][1]);
        acc[rr][2] = fmaf(xs[rr], w0.z, acc[rr][2]);
        acc[rr][3] = fmaf(xs[rr], w0.w, acc[rr][3]);
        acc[rr][4] = fmaf(xs[rr], w1.x, acc[rr][4]);
        acc[rr][5] = fmaf(xs[rr], w1.y, acc[rr][5]);
        acc[rr][6] = fmaf(xs[rr], w1.z, acc[rr][6]);
        acc[rr][7] = fmaf(xs[rr], w1.w, acc[rr][7]);
      }
    }
  }
  float* pb = partial + (size_t)blockIdx.x*8192;
#pragma unroll
  for (int rr=0;rr<4;rr++){
    *(float4*)&pb[(rg+rr)*128 + og]     = *(float4*)&acc[rr][0];
    *(float4*)&pb[(rg+rr)*128 + og + 4] = *(float4*)&acc[rr][4];
  }
}

// ---------------------------------------------------------------------------
// Head (unchanged).
// ---------------------------------------------------------------------------
__global__ __launch_bounds__(256) void dense_head(
    const float* __restrict__ partial,
    const float* __restrict__ db0, const float* __restrict__ dg0,
    const float* __restrict__ dbb0,
    const float* __restrict__ dW1, const float* __restrict__ db1,
    const float* __restrict__ dg1, const float* __restrict__ dbb1,
    const float* __restrict__ W2, const float* __restrict__ b2,
    float* __restrict__ out)
{
  __shared__ float sred[256];
  __shared__ float h[128];
  __shared__ float red0[128], red1[128];
  int tid = threadIdx.x;
  int b = blockIdx.x;
  int o = tid & 127, ph = tid >> 7;
  float s = 0.f;
#pragma unroll 16
  for (int p = ph*128; p < ph*128+128; p++)
    s += partial[(size_t)p*8192 + b*128 + o];
  sred[tid] = s;
  __syncthreads();
  if (tid < 128){
    float sum = sred[tid] + sred[tid+128];
    float v = dg0[tid]*((sum + db0[tid])*INV_S) + dbb0[tid];
    h[tid] = fast_sigmoid(v);
  }
  __syncthreads();
  if (tid < 128){
    float acc = 0.f;
#pragma unroll 8
    for (int k=0;k<128;k++) acc = fmaf(h[k], dW1[k*128 + tid], acc);
    float v = dg1[tid]*((acc + db1[tid])*INV_S) + dbb1[tid];
    float h1 = fast_sigmoid(v);
    red0[tid] = h1 * W2[tid*2+0];
    red1[tid] = h1 * W2[tid*2+1];
  }
  __syncthreads();
  for (int st=64; st>0; st>>=1){
    if (tid < st){ red0[tid] += red0[tid+st]; red1[tid] += red1[tid+st]; }
    __syncthreads();
  }
  if (tid == 0){
    out[b*4+0] = red0[0] + b2[0];
    out[b*4+1] = red1[0] + b2[1];
    out[b*4+2] = 0.f;
    out[b*4+3] = 0.f;
  }
}

// ---------------------------------------------------------------------------
extern "C" void kernel_launch(void* const* d_in, const int* in_sizes, int n_in,
                              void* d_out, int out_size, void* d_ws, size_t ws_size,
                              hipStream_t stream)
{
  const float* xx   = (const float*)d_in[0];
  const float* emb1 = (const float*)d_in[1];
  const float* emb2 = (const float*)d_in[2];
  const float* emb3 = (const float*)d_in[3];
  const float* A0   = (const float*)d_in[4];
  const float* b0   = (const float*)d_in[5];
  const float* Ar   = (const float*)d_in[6];   // (4,129,64)
  const float* br   = (const float*)d_in[7];   // (4,64)
  const float* bng  = (const float*)d_in[8];   // (5,64)
  const float* bnb  = (const float*)d_in[9];   // (5,64)
  const float* dW0  = (const float*)d_in[10];  // (32768,128)
  const float* db0  = (const float*)d_in[11];
  const float* dW1  = (const float*)d_in[12];  // (128,128)
  const float* db1  = (const float*)d_in[13];
  const float* dbg  = (const float*)d_in[14];  // (2,128)
  const float* dbb  = (const float*)d_in[15];
  const float* W2   = (const float*)d_in[16];  // (128,2)
  const float* b2   = (const float*)d_in[17];

  float* ws = (float*)d_ws;
  float*  xA      = ws;                               // 32768*64
  float*  partial = xA + (size_t)R_*64;               // 256*8192
  float4* cb0     = (float4*)(partial + (size_t)256*8192);  // 32768 float4
  float4* cb1     = cb0 + R_;                         // 32768 float4
  unsigned int* bar = (unsigned int*)(cb1 + R_);      // 64*32 uints

  // barrier counters must start at 0 (workspace is poisoned, not zeroed)
  hipMemsetAsync(bar, 0, 64*32*sizeof(unsigned int), stream);

  GnnArgs ga;
  ga.xx = xx; ga.emb1 = emb1; ga.emb2 = emb2; ga.emb3 = emb3;
  ga.A0 = A0; ga.b0 = b0; ga.Ar = Ar; ga.br = br;
  ga.bng = bng; ga.bnb = bnb;
  ga.cb0 = cb0; ga.cb1 = cb1; ga.bar = bar; ga.xfinal = xA;

  // PLAIN launch: co-residency of all 512 blocks is guaranteed by LDS
  // arithmetic (63KB -> 2 blocks/CU x 256 CU = 512 slots = grid).
  hipLaunchKernelGGL(gnn_fused, dim3(64,8), dim3(512), 0, stream, ga);

  dense0_partial<<<256, 256, 0, stream>>>(xA, dW0, partial);
  dense_head<<<B_, 256, 0, stream>>>(partial, db0, dbg, dbb,
                                     dW1, db1, dbg + 128, dbb + 128,
                                     W2, b2, (float*)d_out);
}